// Round 1
// baseline (142.331 us; speedup 1.0000x reference)
//
#include <hip/hip_runtime.h>
#include <hip/hip_bf16.h>

typedef float f32x4 __attribute__((ext_vector_type(4)));
typedef __bf16 bf16x8 __attribute__((ext_vector_type(8)));

// ---------------------------------------------------------------------------
// convert: fp32 -> bf16 for x (2M elems) and Wq/Wk/Wv/Wo (1M each), contiguous
// dst layout: [xb 2M][wqb 1M][wkb 1M][wvb 1M][wob 1M]
// ---------------------------------------------------------------------------
__global__ __launch_bounds__(256) void convert_all(
    const float* __restrict__ x, const float* __restrict__ wq,
    const float* __restrict__ wk, const float* __restrict__ wv,
    const float* __restrict__ wo, __bf16* __restrict__ dst)
{
  int t = blockIdx.x * 256 + threadIdx.x;   // 786432 threads, 8 elems each
  const float* src; size_t soff;
  if (t < 262144) { src = x; soff = (size_t)t * 8; }
  else {
    int r = (t - 262144) >> 17;
    src = (r == 0) ? wq : (r == 1) ? wk : (r == 2) ? wv : wo;
    soff = (size_t)((t - 262144) & 131071) * 8;
  }
  float4 f0 = *(const float4*)(src + soff);
  float4 f1 = *(const float4*)(src + soff + 4);
  bf16x8 o;
  o[0]=(__bf16)f0.x; o[1]=(__bf16)f0.y; o[2]=(__bf16)f0.z; o[3]=(__bf16)f0.w;
  o[4]=(__bf16)f1.x; o[5]=(__bf16)f1.y; o[6]=(__bf16)f1.z; o[7]=(__bf16)f1.w;
  *(bf16x8*)(dst + (size_t)t * 8) = o;
}

// ---------------------------------------------------------------------------
// GEMM: C[m][n] = sum_k A[m][k] * B[n][k]   (B given row-major over k = W[f][e])
// 128x128 tile, BK=32, 4 waves in 2x2 quadrants, 4x4 fragments each.
// LDS XOR swizzle: chunk slot = c ^ ((row>>1)&3)  -> 2-way bank aliasing (free)
// blockIdx.z selects among 3 (B,C) pairs so QKV is one launch.
// ---------------------------------------------------------------------------
template <typename OutT>
__global__ __launch_bounds__(256) void gemm_bt(
    const __bf16* __restrict__ A,
    const __bf16* __restrict__ B0, const __bf16* __restrict__ B1, const __bf16* __restrict__ B2,
    OutT* __restrict__ C0, OutT* __restrict__ C1, OutT* __restrict__ C2,
    int M, int N, int K)
{
  const __bf16* B = (blockIdx.z == 0) ? B0 : (blockIdx.z == 1) ? B1 : B2;
  OutT* C = (blockIdx.z == 0) ? C0 : (blockIdx.z == 1) ? C1 : C2;

  __shared__ __align__(16) __bf16 As[128 * 32];
  __shared__ __align__(16) __bf16 Bs[128 * 32];

  const int tid = threadIdx.x, w = tid >> 6, l = tid & 63;
  const int wr = w >> 1, wc = w & 1;          // wave quadrant (2x2 of 64x64)
  const int g = l >> 4, c16 = l & 15;
  const int bm = blockIdx.y, bn = blockIdx.x;

  f32x4 acc[4][4] = {};
  const int nk = K >> 5;
  const int srow = w * 32 + (l >> 2);         // staging row (+p*16)
  const int sch  = l & 3;                     // staging 16B chunk within 64B row

  for (int kt = 0; kt < nk; ++kt) {
    bf16x8 ra[2], rb[2];
#pragma unroll
    for (int p = 0; p < 2; ++p) {
      int row = srow + p * 16;
      ra[p] = *(const bf16x8*)(A + (size_t)(bm * 128 + row) * K + kt * 32 + sch * 8);
      rb[p] = *(const bf16x8*)(B + (size_t)(bn * 128 + row) * K + kt * 32 + sch * 8);
    }
    __syncthreads();   // previous iteration's MFMA reads done
#pragma unroll
    for (int p = 0; p < 2; ++p) {
      int row = srow + p * 16;
      int slot = sch ^ ((row >> 1) & 3);
      *(bf16x8*)((char*)As + row * 64 + slot * 16) = ra[p];
      *(bf16x8*)((char*)Bs + row * 64 + slot * 16) = rb[p];
    }
    __syncthreads();

    bf16x8 af[4], bff[4];
#pragma unroll
    for (int mt = 0; mt < 4; ++mt) {
      int row = wr * 64 + mt * 16 + c16;
      int slot = g ^ ((row >> 1) & 3);
      af[mt] = *(const bf16x8*)((char*)As + row * 64 + slot * 16);
    }
#pragma unroll
    for (int nt = 0; nt < 4; ++nt) {
      int row = wc * 64 + nt * 16 + c16;
      int slot = g ^ ((row >> 1) & 3);
      bff[nt] = *(const bf16x8*)((char*)Bs + row * 64 + slot * 16);
    }
#pragma unroll
    for (int mt = 0; mt < 4; ++mt)
#pragma unroll
      for (int nt = 0; nt < 4; ++nt)
        acc[mt][nt] = __builtin_amdgcn_mfma_f32_16x16x32_bf16(af[mt], bff[nt], acc[mt][nt], 0, 0, 0);
  }

  // epilogue: C/D layout col = lane&15, row = (lane>>4)*4 + reg   [m89/m91]
#pragma unroll
  for (int mt = 0; mt < 4; ++mt)
#pragma unroll
    for (int nt = 0; nt < 4; ++nt)
#pragma unroll
      for (int r = 0; r < 4; ++r) {
        int row = bm * 128 + wr * 64 + mt * 16 + g * 4 + r;
        int col = bn * 128 + wc * 64 + nt * 16 + c16;
        C[(size_t)row * N + col] = (OutT)acc[mt][nt][r];
      }
}

// ---------------------------------------------------------------------------
// RoPE (half-split) + justnorm + sqk scale for q and k.
// One 32-lane group per (n,h) row; lane i owns pair (i, i+32).
// ---------------------------------------------------------------------------
__global__ __launch_bounds__(256) void rope_norm(
    const __bf16* __restrict__ q, const __bf16* __restrict__ k,
    const float* __restrict__ sqk, __bf16* __restrict__ qo, __bf16* __restrict__ ko)
{
  int gt = blockIdx.x * 256 + threadIdx.x;
  int i = gt & 31;
  int row = gt >> 5;            // n*16 + h, 0..32767
  int h = row & 15;
  int n = row >> 4;

  // inv_freq = 10000^(-i/32) = exp2(-i * log2(10000)/32)
  float inv = exp2f(-(float)i * 0.415241011860919f);
  float ang = (float)n * inv;
  float s, c;
  sincosf(ang, &s, &c);

  const __bf16* qp = q + (size_t)row * 64;
  const __bf16* kp = k + (size_t)row * 64;
  float q1 = (float)qp[i], q2 = (float)qp[i + 32];
  float k1 = (float)kp[i], k2 = (float)kp[i + 32];
  float qa = q1 * c - q2 * s, qb2 = q1 * s + q2 * c;
  float ka = k1 * c - k2 * s, kb2 = k1 * s + k2 * c;

  float ssq = qa * qa + qb2 * qb2;
  float ssk = ka * ka + kb2 * kb2;
#pragma unroll
  for (int m2 = 1; m2 < 32; m2 <<= 1) {
    ssq += __shfl_xor(ssq, m2, 32);
    ssk += __shfl_xor(ssk, m2, 32);
  }
  float rq = rsqrtf(ssq), rk = rsqrtf(ssk);
  float s1 = sqk[h * 64 + i] * 32.0f;        // SQK_INIT_VALUE/SQK_INIT_SCALING = 32
  float s2 = sqk[h * 64 + i + 32] * 32.0f;

  qo[(size_t)row * 64 + i]      = (__bf16)(qa * rq * s1);
  qo[(size_t)row * 64 + i + 32] = (__bf16)(qb2 * rq * s2);
  ko[(size_t)row * 64 + i]      = (__bf16)(ka * rk * s1);
  ko[(size_t)row * 64 + i + 32] = (__bf16)(kb2 * rk * s2);
}

// ---------------------------------------------------------------------------
// V transpose: vt[h][d][n] = v[n][h*64+d]  (bf16), LDS-tiled 64x64
// ---------------------------------------------------------------------------
__global__ __launch_bounds__(256) void vtrans(const __bf16* __restrict__ v, __bf16* __restrict__ vt)
{
  __shared__ __align__(16) __bf16 t[64 * 72];   // pad 8 to break write/read bank patterns
  int h = blockIdx.y;
  int n0 = blockIdx.x * 64;
  int tid = threadIdx.x;
#pragma unroll
  for (int j = 0; j < 2; ++j) {
    int idx = tid + j * 256;
    int r = idx >> 3, c = (idx & 7) * 8;
    bf16x8 val = *(const bf16x8*)(v + (size_t)(n0 + r) * 1024 + h * 64 + c);
    *(bf16x8*)&t[r * 72 + c] = val;
  }
  __syncthreads();
#pragma unroll
  for (int j = 0; j < 2; ++j) {
    int idx = tid + j * 256;
    int d = idx >> 3, nn = (idx & 7) * 8;
    bf16x8 o;
#pragma unroll
    for (int jj = 0; jj < 8; ++jj) o[jj] = t[(nn + jj) * 72 + d];
    *(bf16x8*)(vt + (size_t)(h * 64 + d) * 2048 + n0 + nn) = o;
  }
}

// ---------------------------------------------------------------------------
// Flash-style causal attention. Block = (qt, h): 64 q-rows, 4 waves x 16 rows.
// KV tiles of 64. scores = (q.k)*8, online softmax, O = P V.
// LDS tiles swizzled: slot = chunk ^ (row&7) (row stride 128B would be 16-way).
// ---------------------------------------------------------------------------
__global__ __launch_bounds__(256) void attn_kernel(
    const __bf16* __restrict__ Qg, const __bf16* __restrict__ Kg,
    const __bf16* __restrict__ Vg, __bf16* __restrict__ Og)
{
  __shared__ __align__(16) __bf16 Qs[64 * 64];
  __shared__ __align__(16) __bf16 Ks[64 * 64];
  __shared__ __align__(16) __bf16 Vs[64 * 64];
  __shared__ __align__(16) __bf16 Ps[4][16 * 80];   // per-wave P, padded rows (160B)

  const int h = blockIdx.y, qt = blockIdx.x;
  const int tid = threadIdx.x, w = tid >> 6, l = tid & 63;
  const int g = l >> 4, c16 = l & 15;

  // stage Q tile (wave w: rows w*16 .. w*16+15)
#pragma unroll
  for (int p = 0; p < 2; ++p) {
    int row = w * 16 + p * 8 + (l >> 3);
    bf16x8 val = *(const bf16x8*)(Qg + (size_t)(qt * 64 + row) * 1024 + h * 64 + (l & 7) * 8);
    int slot = (l & 7) ^ (row & 7);
    *(bf16x8*)((char*)Qs + row * 128 + slot * 16) = val;
  }

  f32x4 o[4] = {};
  float mrow[4], lrow[4];
#pragma unroll
  for (int r = 0; r < 4; ++r) { mrow[r] = -1e30f; lrow[r] = 0.f; }

  for (int kt = 0; kt <= qt; ++kt) {
    bf16x8 kreg[2], vreg[2];
#pragma unroll
    for (int p = 0; p < 2; ++p) {
      int row = w * 16 + p * 8 + (l >> 3);
      kreg[p] = *(const bf16x8*)(Kg + (size_t)(kt * 64 + row) * 1024 + h * 64 + (l & 7) * 8);
      vreg[p] = *(const bf16x8*)(Vg + ((size_t)h * 64 + row) * 2048 + kt * 64 + (l & 7) * 8);
    }
    __syncthreads();   // previous iteration's PV reads done
#pragma unroll
    for (int p = 0; p < 2; ++p) {
      int row = w * 16 + p * 8 + (l >> 3);
      int slot = (l & 7) ^ (row & 7);
      *(bf16x8*)((char*)Ks + row * 128 + slot * 16) = kreg[p];
      *(bf16x8*)((char*)Vs + row * 128 + slot * 16) = vreg[p];
    }
    __syncthreads();

    // S = Q K^T (wave strip: 16 q-rows x 64 kj)
    f32x4 s[4] = {};
#pragma unroll
    for (int ks = 0; ks < 2; ++ks) {
      int arow = w * 16 + c16;
      int aslot = (ks * 4 + g) ^ (arow & 7);
      bf16x8 a = *(const bf16x8*)((char*)Qs + arow * 128 + aslot * 16);
#pragma unroll
      for (int nt = 0; nt < 4; ++nt) {
        int brow = nt * 16 + c16;
        int bslot = (ks * 4 + g) ^ (brow & 7);
        bf16x8 b = *(const bf16x8*)((char*)Ks + brow * 128 + bslot * 16);
        s[nt] = __builtin_amdgcn_mfma_f32_16x16x32_bf16(a, b, s[nt], 0, 0, 0);
      }
    }

    // online softmax (per row r, stats reduced across the 16-lane group)
    const bool diag = (kt == qt);
    float corr[4];
    float p[4][4];
#pragma unroll
    for (int r = 0; r < 4; ++r) {
      float smax = -1e30f;
#pragma unroll
      for (int nt = 0; nt < 4; ++nt) {
        float sv = s[nt][r] * 8.0f;                       // scale = sqrt(64)
        if (diag && (nt * 16 + c16) > (w * 16 + g * 4 + r)) sv = -1e30f;
        p[nt][r] = sv;
        smax = fmaxf(smax, sv);
      }
#pragma unroll
      for (int m2 = 1; m2 < 16; m2 <<= 1) smax = fmaxf(smax, __shfl_xor(smax, m2, 16));
      float mnew = fmaxf(mrow[r], smax);
      float cr = __expf(mrow[r] - mnew);
      corr[r] = cr;
      mrow[r] = mnew;
      float psum = 0.f;
#pragma unroll
      for (int nt = 0; nt < 4; ++nt) {
        float pv = __expf(p[nt][r] - mnew);
        p[nt][r] = pv;
        psum += pv;
      }
#pragma unroll
      for (int m2 = 1; m2 < 16; m2 <<= 1) psum += __shfl_xor(psum, m2, 16);
      lrow[r] = lrow[r] * cr + psum;
    }
#pragma unroll
    for (int nt = 0; nt < 4; ++nt)
#pragma unroll
      for (int r = 0; r < 4; ++r)
        o[nt][r] *= corr[r];

    // P -> LDS (bf16), per-wave buffer, rows padded to 80 elems
#pragma unroll
    for (int nt = 0; nt < 4; ++nt)
#pragma unroll
      for (int r = 0; r < 4; ++r)
        Ps[w][(g * 4 + r) * 80 + nt * 16 + c16] = (__bf16)p[nt][r];

    // O += P V   (A = P[qi][kj], B = Vt[d][kj] k-contiguous)
#pragma unroll
    for (int ks = 0; ks < 2; ++ks) {
      bf16x8 a = *(const bf16x8*)((char*)&Ps[w][0] + c16 * 160 + ks * 64 + g * 16);
#pragma unroll
      for (int nt = 0; nt < 4; ++nt) {
        int vrow = nt * 16 + c16;
        int vslot = (ks * 4 + g) ^ (vrow & 7);
        bf16x8 b = *(const bf16x8*)((char*)Vs + vrow * 128 + vslot * 16);
        o[nt] = __builtin_amdgcn_mfma_f32_16x16x32_bf16(a, b, o[nt], 0, 0, 0);
      }
    }
  }

  // epilogue: divide by row sum, write [n][h*64+d]
#pragma unroll
  for (int r = 0; r < 4; ++r) {
    float rinv = 1.0f / lrow[r];
#pragma unroll
    for (int nt = 0; nt < 4; ++nt) {
      int qi = qt * 64 + w * 16 + g * 4 + r;
      int e = h * 64 + nt * 16 + c16;
      Og[(size_t)qi * 1024 + e] = (__bf16)(o[nt][r] * rinv);
    }
  }
}

// ---------------------------------------------------------------------------
extern "C" void kernel_launch(void* const* d_in, const int* in_sizes, int n_in,
                              void* d_out, int out_size, void* d_ws, size_t ws_size,
                              hipStream_t stream) {
  const float* x   = (const float*)d_in[0];
  const float* Wq  = (const float*)d_in[1];
  const float* Wk  = (const float*)d_in[2];
  const float* Wv  = (const float*)d_in[3];
  const float* Wo  = (const float*)d_in[4];
  const float* sqk = (const float*)d_in[5];
  float* out = (float*)d_out;

  // workspace layout (bf16 elems): 18M elems = 36 MiB
  __bf16* xb  = (__bf16*)d_ws;                  // [2048][1024]
  __bf16* wqb = xb  + (size_t)2048 * 1024;      // [1024][1024]
  __bf16* wkb = wqb + (size_t)1024 * 1024;
  __bf16* wvb = wkb + (size_t)1024 * 1024;
  __bf16* wob = wvb + (size_t)1024 * 1024;
  __bf16* q   = wob + (size_t)1024 * 1024;      // [2048][1024]
  __bf16* k   = q   + (size_t)2048 * 1024;
  __bf16* v   = k   + (size_t)2048 * 1024;
  __bf16* qn  = v   + (size_t)2048 * 1024;
  __bf16* kn  = qn  + (size_t)2048 * 1024;
  __bf16* vtb = kn  + (size_t)2048 * 1024;      // [16][64][2048]
  __bf16* og  = vtb + (size_t)2048 * 1024;      // [2048][1024]

  convert_all<<<3072, 256, 0, stream>>>(x, Wq, Wk, Wv, Wo, xb);
  gemm_bt<__bf16><<<dim3(8, 16, 3), 256, 0, stream>>>(
      xb, wqb, wkb, wvb, q, k, v, 2048, 1024, 1024);
  rope_norm<<<4096, 256, 0, stream>>>(q, k, sqk, qn, kn);
  vtrans<<<dim3(32, 16), 256, 0, stream>>>(v, vtb);
  attn_kernel<<<dim3(32, 16), 256, 0, stream>>>(qn, kn, vtb, og);
  gemm_bt<float><<<dim3(8, 16, 1), 256, 0, stream>>>(
      og, wob, wob, wob, out, out, out, 2048, 1024, 1024);
}